// Round 6
// baseline (148.261 us; speedup 1.0000x reference)
//
#include <hip/hip_runtime.h>

// ---------------------------------------------------------------------------
// SwitchGLU MoE, round 6: 3-buffer counted-vmcnt pipeline (T4).
//  - STAGE(kt+2) issued before COMPUTE(kt); s_waitcnt vmcnt(N) with N = one
//    stage's load count -> next tile's loads stay in flight ACROSS the barrier
//  - 3 LDS buffers (hazard-free deep prefetch); stage1 96KB, stage2 48KB
//  - global_load_lds staging, pre-swizzled global source, same-XOR LDS reads
// ---------------------------------------------------------------------------

typedef unsigned short u16;
typedef unsigned int   u32;
typedef u16    u16x8 __attribute__((ext_vector_type(8)));
typedef __bf16 bf16x8 __attribute__((ext_vector_type(8)));
typedef float  f32x4 __attribute__((ext_vector_type(4)));

#define NE   8
#define DDIM 768
#define HDIM 2048
#define NTOT 2048
#define MAXT 24

__device__ __forceinline__ u16 f2bf(float f) {
  return (u16)((__builtin_bit_cast(u32, f) + 0x8000u) >> 16);
}
__device__ __forceinline__ bf16x8 cvt8(float4 a, float4 b) {
  bf16x8 r;
  r[0] = (__bf16)a.x; r[1] = (__bf16)a.y; r[2] = (__bf16)a.z; r[3] = (__bf16)a.w;
  r[4] = (__bf16)b.x; r[5] = (__bf16)b.y; r[6] = (__bf16)b.z; r[7] = (__bf16)b.w;
  return r;
}
__device__ __forceinline__ bf16x8 fragb(const u16* p) {
  return __builtin_bit_cast(bf16x8, *reinterpret_cast<const u16x8*>(p));
}
__device__ __forceinline__ f32x4 mfma(bf16x8 a, bf16x8 b, f32x4 c) {
  return __builtin_amdgcn_mfma_f32_16x16x32_bf16(a, b, c, 0, 0, 0);
}
__device__ __forceinline__ void gl16(const void* g, void* l) {
  __builtin_amdgcn_global_load_lds(
      (const __attribute__((address_space(1))) void*)g,
      (__attribute__((address_space(3))) void*)l, 16, 0, 0);
}
// counted-wait phase end: N oldest loads must complete; newest stay in flight
#define PHASE_SYNC(N) do {                                              \
    __builtin_amdgcn_sched_barrier(0);                                  \
    asm volatile("s_waitcnt vmcnt(" #N ") lgkmcnt(0)" ::: "memory");    \
    __builtin_amdgcn_s_barrier();                                       \
    __builtin_amdgcn_sched_barrier(0);                                  \
  } while (0)

// ---------------------------------------------------------------------------
// Dispatch: bucket token-pairs by expert + 128-row tile table.
// meta[0..8]=offs, meta[15]=ntiles, meta[16+t]=expert, meta[48+t]=row0.
// ---------------------------------------------------------------------------
__global__ void moe_dispatch(const int* __restrict__ idx,
                             int* __restrict__ meta, int* __restrict__ perm) {
  __shared__ int s_cnt[NE];
  __shared__ int s_off[NE + 1];
  __shared__ int s_cur[NE];
  const int tid = threadIdx.x;
  if (tid < NE) { s_cnt[tid] = 0; s_cur[tid] = 0; }
  __syncthreads();
  for (int n = tid; n < NTOT; n += 256) atomicAdd(&s_cnt[idx[n]], 1);
  __syncthreads();
  if (tid == 0) {
    int a = 0;
    for (int e = 0; e < NE; ++e) { s_off[e] = a; a += s_cnt[e]; }
    s_off[NE] = a;
  }
  __syncthreads();
  for (int n = tid; n < NTOT; n += 256) {
    const int e = idx[n];
    perm[s_off[e] + atomicAdd(&s_cur[e], 1)] = n;
  }
  if (tid == 0) {
    int tc = 0;
    for (int e = 0; e < NE; ++e) {
      for (int r0 = s_off[e]; r0 < s_off[e + 1]; r0 += 128) {
        meta[16 + tc] = e;
        meta[48 + tc] = r0;
        ++tc;
      }
    }
    meta[15] = tc;
  }
  if (tid < NE + 1) meta[tid] = s_off[tid];
}

// ---------------------------------------------------------------------------
// Stage 1: h = silu(X Wg^T) * (X Wu^T).  BM=128, BN=64(G)+64(U), BK=32.
// grid = MAXT*32 flat. 256 thr = 4 waves (2M x 2N), wave = 64M x 32N of both.
// 3 LDS buffers (96KB), counted vmcnt(8) per phase.
// ---------------------------------------------------------------------------
__global__ __launch_bounds__(256) void moe_stage1(
    const float* __restrict__ x, const int* __restrict__ perm,
    const int* __restrict__ meta, const float* __restrict__ wg,
    const float* __restrict__ wu, u16* __restrict__ hbuf) {
  const int t = blockIdx.x >> 5;
  if (t >= meta[15]) return;
  const int nt = blockIdx.x & 31;
  const int e = meta[16 + t];
  const int r0 = meta[48 + t];
  const int rows = min(128, meta[e + 1] - r0);

  __shared__ __align__(16) float sX[3][128 * 32];
  __shared__ __align__(16) float sG[3][64 * 32];
  __shared__ __align__(16) float sU[3][64 * 32];

  const int tid = threadIdx.x;
  const int lane = tid & 63;
  const int wv = tid >> 6;
  const int wm = (wv >> 1) * 64;
  const int wn = (wv & 1) * 32;

  // staging: fp32 rows = 8 chunks of 16B; lane L -> (row L>>3, chunk L&7),
  // source chunk pre-swizzled (L&7)^(row&7); LDS dest linear.
  const int lr = lane >> 3, lc = lane & 7;
  const float* gpX[4];
  int lbX[4];
#pragma unroll
  for (int j = 0; j < 4; ++j) {
    const int r = wv * 32 + j * 8 + lr;
    const int tok = perm[r0 + min(r, rows - 1)] >> 1;  // TOPK=2
    gpX[j] = x + (size_t)tok * DDIM + ((lc ^ (r & 7)) << 2);
    lbX[j] = (wv * 32 + j * 8) * 32;
  }
  const float* gpG[2];
  const float* gpU[2];
  int lbW[2];
#pragma unroll
  for (int j = 0; j < 2; ++j) {
    const int r = wv * 16 + j * 8 + lr;
    const size_t row = (size_t)e * HDIM + nt * 64 + r;
    gpG[j] = wg + row * DDIM + ((lc ^ (r & 7)) << 2);
    gpU[j] = wu + row * DDIM + ((lc ^ (r & 7)) << 2);
    lbW[j] = (wv * 16 + j * 8) * 32;
  }

  f32x4 aG[4][2] = {};
  f32x4 aU[4][2] = {};

  // 8 gl_lds per wave per stage
#define S1_STAGE(b) do {                                                  \
    _Pragma("unroll") for (int j = 0; j < 4; ++j)                         \
      gl16(gpX[j], &sX[b][lbX[j]]);                                       \
    _Pragma("unroll") for (int j = 0; j < 2; ++j) {                       \
      gl16(gpG[j], &sG[b][lbW[j]]);                                       \
      gl16(gpU[j], &sU[b][lbW[j]]);                                       \
    }                                                                     \
    _Pragma("unroll") for (int j = 0; j < 4; ++j) gpX[j] += 32;           \
    _Pragma("unroll") for (int j = 0; j < 2; ++j) { gpG[j] += 32; gpU[j] += 32; } \
  } while (0)

#define RD8(tile, r_, kb_) cvt8(                                              \
    *(const float4*)&(tile)[(r_) * 32 + ((((kb_) * 2    ) ^ ((r_) & 7)) << 2)], \
    *(const float4*)&(tile)[(r_) * 32 + ((((kb_) * 2 + 1) ^ ((r_) & 7)) << 2)])

#define S1_COMPUTE(b) do {                                   \
    const int fr_ = lane & 15, kb_ = lane >> 4;              \
    bf16x8 a_[4], g_[2], u_[2];                              \
    _Pragma("unroll") for (int mi = 0; mi < 4; ++mi)         \
      a_[mi] = RD8(sX[b], wm + mi * 16 + fr_, kb_);          \
    _Pragma("unroll") for (int nj = 0; nj < 2; ++nj) {       \
      g_[nj] = RD8(sG[b], wn + nj * 16 + fr_, kb_);          \
      u_[nj] = RD8(sU[b], wn + nj * 16 + fr_, kb_);          \
    }                                                        \
    _Pragma("unroll") for (int mi = 0; mi < 4; ++mi)         \
      _Pragma("unroll") for (int nj = 0; nj < 2; ++nj) {     \
        aG[mi][nj] = mfma(a_[mi], g_[nj], aG[mi][nj]);       \
        aU[mi][nj] = mfma(a_[mi], u_[nj], aU[mi][nj]);       \
      }                                                      \
  } while (0)

  // prologue: fill pipe 2 deep
  S1_STAGE(0);
  S1_STAGE(1);
  PHASE_SYNC(8);  // S0 done; S1 in flight

  int cb = 0, sb = 2;
#pragma unroll 1
  for (int kt = 0; kt + 2 < 24; ++kt) {  // kt = 0..21
    switch (sb) {  // static buffer index for STAGE
      case 0: S1_STAGE(0); break;
      case 1: S1_STAGE(1); break;
      default: S1_STAGE(2); break;
    }
    __builtin_amdgcn_sched_barrier(0);
    switch (cb) {
      case 0: S1_COMPUTE(0); break;
      case 1: S1_COMPUTE(1); break;
      default: S1_COMPUTE(2); break;
    }
    PHASE_SYNC(8);  // S_{kt+1} done; S_{kt+2} in flight
    cb = (cb == 2) ? 0 : cb + 1;
    sb = (sb == 2) ? 0 : sb + 1;
  }
  // tail: kt=22 (cb=1), kt=23 (cb=2)
  S1_COMPUTE(1);
  PHASE_SYNC(0);
  S1_COMPUTE(2);

  // epilogue: C/D layout col=lane&15, row=(lane>>4)*4+reg
  const int crow = (lane >> 4) << 2;
  const int ccol = lane & 15;
#pragma unroll
  for (int mi = 0; mi < 4; ++mi) {
#pragma unroll
    for (int ri = 0; ri < 4; ++ri) {
      const int lm = wm + mi * 16 + crow + ri;
      if (lm < rows) {
        u16* hb = hbuf + (size_t)(r0 + lm) * HDIM + nt * 64 + wn;
#pragma unroll
        for (int nj = 0; nj < 2; ++nj) {
          const float g = aG[mi][nj][ri];
          const float u = aU[mi][nj][ri];
          const float h = g / (1.0f + __expf(-g)) * u;
          hb[nj * 16 + ccol] = f2bf(h);
        }
      }
    }
  }
}

// ---------------------------------------------------------------------------
// Stage 2: out[tok,:] += h Wd^T.  BM=128, BN=64, BK=32, split-K=2.
// grid = MAXT*24 flat. 3 LDS buffers (48KB), counted vmcnt(4) per phase.
// ---------------------------------------------------------------------------
__global__ __launch_bounds__(256, 3) void moe_stage2(
    const u16* __restrict__ hbuf, const int* __restrict__ perm,
    const int* __restrict__ meta, const float* __restrict__ wd,
    float* __restrict__ out) {
  const int t = blockIdx.x / 24;
  if (t >= meta[15]) return;
  const int rem = blockIdx.x - t * 24;
  const int ks = rem / 12;
  const int nt = rem - ks * 12;
  const int e = meta[16 + t];
  const int r0 = meta[48 + t];
  const int rows = min(128, meta[e + 1] - r0);

  __shared__ __align__(16) u16   sA[3][128 * 32];
  __shared__ __align__(16) float sB[3][64 * 32];

  const int tid = threadIdx.x;
  const int lane = tid & 63;
  const int wv = tid >> 6;
  const int wm = (wv >> 1) * 64;
  const int wn = (wv & 1) * 32;

  // A (bf16): 64B rows = 4 chunks; lane L -> (row L>>2, chunk L&3),
  // source chunk (L&3)^((row>>1)&3).
  const u16* gpA[2];
  int lbA[2];
#pragma unroll
  for (int j = 0; j < 2; ++j) {
    const int r = wv * 32 + j * 16 + (lane >> 2);
    gpA[j] = hbuf + (size_t)(r0 + min(r, rows - 1)) * HDIM + ks * 1024 +
             (((lane & 3) ^ ((r >> 1) & 3)) << 3);
    lbA[j] = (wv * 32 + j * 16) * 32;
  }
  // B (fp32): 128B rows = 8 chunks, as stage1 weights.
  const float* gpB[2];
  int lbB[2];
#pragma unroll
  for (int j = 0; j < 2; ++j) {
    const int r = wv * 16 + j * 8 + (lane >> 3);
    gpB[j] = wd + ((size_t)e * DDIM + nt * 64 + r) * HDIM + ks * 1024 +
             (((lane & 7) ^ (r & 7)) << 2);
    lbB[j] = (wv * 16 + j * 8) * 32;
  }

  f32x4 acc[4][2] = {};

  // 4 gl_lds per wave per stage
#define S2_STAGE(b) do {                                                  \
    _Pragma("unroll") for (int j = 0; j < 2; ++j) {                       \
      gl16(gpA[j], &sA[b][lbA[j]]);                                       \
      gl16(gpB[j], &sB[b][lbB[j]]);                                       \
    }                                                                     \
    _Pragma("unroll") for (int j = 0; j < 2; ++j) { gpA[j] += 32; gpB[j] += 32; } \
  } while (0)

#define S2_COMPUTE(b) do {                                   \
    const int fr_ = lane & 15, kb_ = lane >> 4;              \
    bf16x8 a_[4], b_[2];                                     \
    _Pragma("unroll") for (int mi = 0; mi < 4; ++mi) {       \
      const int r_ = wm + mi * 16 + fr_;                     \
      a_[mi] = fragb(&sA[b][r_ * 32 + ((kb_ ^ ((r_ >> 1) & 3)) << 3)]); \
    }                                                        \
    _Pragma("unroll") for (int nj = 0; nj < 2; ++nj)         \
      b_[nj] = RD8(sB[b], wn + nj * 16 + fr_, kb_);          \
    _Pragma("unroll") for (int mi = 0; mi < 4; ++mi)         \
      _Pragma("unroll") for (int nj = 0; nj < 2; ++nj)       \
        acc[mi][nj] = mfma(a_[mi], b_[nj], acc[mi][nj]);     \
  } while (0)

  S2_STAGE(0);
  S2_STAGE(1);
  PHASE_SYNC(4);

  int cb = 0, sb = 2;
#pragma unroll 1
  for (int kt = 0; kt + 2 < 32; ++kt) {  // kt = 0..29
    switch (sb) {
      case 0: S2_STAGE(0); break;
      case 1: S2_STAGE(1); break;
      default: S2_STAGE(2); break;
    }
    __builtin_amdgcn_sched_barrier(0);
    switch (cb) {
      case 0: S2_COMPUTE(0); break;
      case 1: S2_COMPUTE(1); break;
      default: S2_COMPUTE(2); break;
    }
    PHASE_SYNC(4);
    cb = (cb == 2) ? 0 : cb + 1;
    sb = (sb == 2) ? 0 : sb + 1;
  }
  // tail: kt=30 (cb=0), kt=31 (cb=1)
  S2_COMPUTE(0);
  PHASE_SYNC(0);
  S2_COMPUTE(1);

  const int crow = (lane >> 4) << 2;
  const int ccol = lane & 15;
#pragma unroll
  for (int mi = 0; mi < 4; ++mi) {
#pragma unroll
    for (int ri = 0; ri < 4; ++ri) {
      const int lm = wm + mi * 16 + crow + ri;
      if (lm < rows) {
        const int tok = perm[r0 + lm];
        float* orow = out + (size_t)tok * DDIM + nt * 64 + wn;
#pragma unroll
        for (int nj = 0; nj < 2; ++nj) {
          atomicAdd(&orow[nj * 16 + ccol], acc[mi][nj][ri]);
        }
      }
    }
  }
}

// ---------------------------------------------------------------------------
extern "C" void kernel_launch(void* const* d_in, const int* in_sizes, int n_in,
                              void* d_out, int out_size, void* d_ws, size_t ws_size,
                              hipStream_t stream) {
  const float* x  = (const float*)d_in[0];
  const int* idx  = (const int*)d_in[1];
  const float* wg = (const float*)d_in[2];
  const float* wu = (const float*)d_in[3];
  const float* wd = (const float*)d_in[4];
  float* out = (float*)d_out;

  int* iws = (int*)d_ws;
  int* meta = iws;        // [0..8] offs, [15] ntiles, [16..47] e, [48..79] r0
  int* perm = iws + 128;  // 2048 ints
  u16* hbuf = (u16*)((char*)d_ws + 16384);  // 2048*2048 bf16 = 8 MB

  hipMemsetAsync(d_out, 0, (size_t)out_size * sizeof(float), stream);
  moe_dispatch<<<1, 256, 0, stream>>>(idx, meta, perm);
  moe_stage1<<<MAXT * 32, 256, 0, stream>>>(x, perm, meta, wg, wu, hbuf);
  moe_stage2<<<MAXT * 24, 256, 0, stream>>>(hbuf, perm, meta, wd, out);
}

// Round 7
// 118.228 us; speedup vs baseline: 1.2540x; 1.2540x over previous
//
#include <hip/hip_runtime.h>

// ---------------------------------------------------------------------------
// SwitchGLU MoE, round 7: bf16-in-LDS reg-staged pipeline (T14 split).
//  - LDS holds bf16 (halves LDS read+write bytes vs fp32; fixes the measured
//    LDS-BW bound). fp32->bf16 cvt in regs during staging.
//  - 8B-chunk XOR swizzle (c ^= r&15): ds_read_b64/ds_write_b64 are 2-way
//    per dword-phase = conflict-free (the 16B-chunk layout was a structural
//    4-way: 4.1M conflicts constant across R4-R6).
//  - T14: loads(kt+1) issued BEFORE compute(kt); vmcnt(0) after compute ->
//    HBM/L2 latency hides under MFMA. Write(kt+1) after barrier.
//  - BK=64 -> 12/16 phases. 2-buffer. Dense tile table. split-K=2 stage2.
// ---------------------------------------------------------------------------

typedef unsigned short u16;
typedef unsigned int   u32;
typedef __bf16 bf16x8 __attribute__((ext_vector_type(8)));
typedef float  f32x4 __attribute__((ext_vector_type(4)));

#define NE   8
#define DDIM 768
#define HDIM 2048
#define NTOT 2048
#define MAXT 24

__device__ __forceinline__ u16 f2bf(float f) {
  return (u16)((__builtin_bit_cast(u32, f) + 0x8000u) >> 16);
}
// float4 -> 4 bf16 (8B), RNE via compiler cvt_pk
__device__ __forceinline__ uint2 cvt2(float4 f) {
  union { u16 h[4]; uint2 v; } u;
  u.h[0] = __builtin_bit_cast(u16, (__bf16)f.x);
  u.h[1] = __builtin_bit_cast(u16, (__bf16)f.y);
  u.h[2] = __builtin_bit_cast(u16, (__bf16)f.z);
  u.h[3] = __builtin_bit_cast(u16, (__bf16)f.w);
  return u.v;
}
// read one MFMA operand fragment (8 bf16 = k 4c0..4c0+7) from a swizzled row
__device__ __forceinline__ bf16x8 frag8(const u16* tile, int r, int c0) {
  const int key = r & 15;
  const u16* row = tile + r * 64;
  uint2 lo = *reinterpret_cast<const uint2*>(row + ((c0 ^ key) << 2));
  uint2 hi = *reinterpret_cast<const uint2*>(row + (((c0 + 1) ^ key) << 2));
  uint4 v = {lo.x, lo.y, hi.x, hi.y};
  return __builtin_bit_cast(bf16x8, v);
}
__device__ __forceinline__ f32x4 mfma(bf16x8 a, bf16x8 b, f32x4 c) {
  return __builtin_amdgcn_mfma_f32_16x16x32_bf16(a, b, c, 0, 0, 0);
}
// after compute: loads arrived + everyone's LDS reads done, then barrier
#define SYNC_RW() do {                                               \
    __builtin_amdgcn_sched_barrier(0);                               \
    asm volatile("s_waitcnt vmcnt(0) lgkmcnt(0)" ::: "memory");      \
    __builtin_amdgcn_s_barrier();                                    \
    __builtin_amdgcn_sched_barrier(0);                               \
  } while (0)
// after ds_write: writes visible, then barrier
#define SYNC_W() do {                                                \
    __builtin_amdgcn_sched_barrier(0);                               \
    asm volatile("s_waitcnt lgkmcnt(0)" ::: "memory");               \
    __builtin_amdgcn_s_barrier();                                    \
    __builtin_amdgcn_sched_barrier(0);                               \
  } while (0)

// ---------------------------------------------------------------------------
// Dispatch: bucket token-pairs by expert + 128-row tile table.
// ---------------------------------------------------------------------------
__global__ void moe_dispatch(const int* __restrict__ idx,
                             int* __restrict__ meta, int* __restrict__ perm) {
  __shared__ int s_cnt[NE];
  __shared__ int s_off[NE + 1];
  __shared__ int s_cur[NE];
  const int tid = threadIdx.x;
  if (tid < NE) { s_cnt[tid] = 0; s_cur[tid] = 0; }
  __syncthreads();
  for (int n = tid; n < NTOT; n += 256) atomicAdd(&s_cnt[idx[n]], 1);
  __syncthreads();
  if (tid == 0) {
    int a = 0;
    for (int e = 0; e < NE; ++e) { s_off[e] = a; a += s_cnt[e]; }
    s_off[NE] = a;
  }
  __syncthreads();
  for (int n = tid; n < NTOT; n += 256) {
    const int e = idx[n];
    perm[s_off[e] + atomicAdd(&s_cur[e], 1)] = n;
  }
  if (tid == 0) {
    int tc = 0;
    for (int e = 0; e < NE; ++e) {
      for (int r0 = s_off[e]; r0 < s_off[e + 1]; r0 += 128) {
        meta[16 + tc] = e;
        meta[48 + tc] = r0;
        ++tc;
      }
    }
    meta[15] = tc;
  }
  if (tid < NE + 1) meta[tid] = s_off[tid];
}

// ---------------------------------------------------------------------------
// Stage 1: h = silu(X Wg^T) * (X Wu^T).  BM=128, BN=64(G)+64(U), BK=64.
// grid = MAXT*32 flat. 256 thr = 4 waves (2M x 2N), wave = 64M x 32N of both.
// LDS 64KB (2 blocks/CU). 12 phases.
// ---------------------------------------------------------------------------
__global__ __launch_bounds__(256, 2) void moe_stage1(
    const float* __restrict__ x, const int* __restrict__ perm,
    const int* __restrict__ meta, const float* __restrict__ wg,
    const float* __restrict__ wu, u16* __restrict__ hbuf) {
  const int t = blockIdx.x >> 5;
  if (t >= meta[15]) return;
  const int nt = blockIdx.x & 31;
  const int e = meta[16 + t];
  const int r0 = meta[48 + t];
  const int rows = min(128, meta[e + 1] - r0);

  __shared__ __align__(16) u16 sX[2][128 * 64];
  __shared__ __align__(16) u16 sG[2][64 * 64];
  __shared__ __align__(16) u16 sU[2][64 * 64];

  const int tid = threadIdx.x;
  const int lane = tid & 63;
  const int wv = tid >> 6;
  const int wm = (wv >> 1) * 64;  // 0,64
  const int wn = (wv & 1) * 32;   // 0,32

  // X staging: thread -> (row xr=tid>>1, half xh=tid&1); 32 floats/phase
  const int xr = tid >> 1, xh = tid & 1;
  const int tok = perm[r0 + min(xr, rows - 1)] >> 1;  // TOPK=2
  const float* xp = x + (size_t)tok * DDIM + xh * 32;
  // W staging: thread -> (row wr=tid>>2, quarter wq=tid&3); 16 floats each
  const int wr = tid >> 2, wq = tid & 3;
  const float* gp = wg + ((size_t)e * HDIM + nt * 64 + wr) * DDIM + wq * 16;
  const float* up = wu + ((size_t)e * HDIM + nt * 64 + wr) * DDIM + wq * 16;

  f32x4 aG[4][2] = {};
  f32x4 aU[4][2] = {};
  float4 lx[8], lg[4], lu[4];

#define S1_LOADS(kt) do {                                            \
    const float4* q_;                                                \
    q_ = (const float4*)(xp + (kt) * 64);                            \
    _Pragma("unroll") for (int j = 0; j < 8; ++j) lx[j] = q_[j];     \
    q_ = (const float4*)(gp + (kt) * 64);                            \
    _Pragma("unroll") for (int j = 0; j < 4; ++j) lg[j] = q_[j];     \
    q_ = (const float4*)(up + (kt) * 64);                            \
    _Pragma("unroll") for (int j = 0; j < 4; ++j) lu[j] = q_[j];     \
  } while (0)

#define S1_WRITE(b) do {                                                     \
    const int xkey_ = xr & 15, wkey_ = wr & 15;                              \
    _Pragma("unroll") for (int j = 0; j < 8; ++j)                            \
      *(uint2*)&sX[b][xr * 64 + (((xh * 8 + j) ^ xkey_) << 2)] = cvt2(lx[j]);\
    _Pragma("unroll") for (int j = 0; j < 4; ++j) {                          \
      *(uint2*)&sG[b][wr * 64 + (((wq * 4 + j) ^ wkey_) << 2)] = cvt2(lg[j]);\
      *(uint2*)&sU[b][wr * 64 + (((wq * 4 + j) ^ wkey_) << 2)] = cvt2(lu[j]);\
    }                                                                        \
  } while (0)

#define S1_COMPUTE(b) do {                                           \
    const int fr_ = lane & 15, kb_ = lane >> 4;                      \
    _Pragma("unroll") for (int kh = 0; kh < 2; ++kh) {               \
      const int c0_ = kh * 8 + kb_ * 2;                              \
      bf16x8 a_[4], g_[2], u_[2];                                    \
      _Pragma("unroll") for (int mi = 0; mi < 4; ++mi)               \
        a_[mi] = frag8(sX[b], wm + mi * 16 + fr_, c0_);              \
      _Pragma("unroll") for (int nj = 0; nj < 2; ++nj) {             \
        g_[nj] = frag8(sG[b], wn + nj * 16 + fr_, c0_);              \
        u_[nj] = frag8(sU[b], wn + nj * 16 + fr_, c0_);              \
      }                                                              \
      _Pragma("unroll") for (int mi = 0; mi < 4; ++mi)               \
        _Pragma("unroll") for (int nj = 0; nj < 2; ++nj) {           \
          aG[mi][nj] = mfma(a_[mi], g_[nj], aG[mi][nj]);             \
          aU[mi][nj] = mfma(a_[mi], u_[nj], aU[mi][nj]);             \
        }                                                            \
    }                                                                \
  } while (0)

  S1_LOADS(0);
  asm volatile("s_waitcnt vmcnt(0)" ::: "memory");
  S1_WRITE(0);
  SYNC_W();

#pragma unroll 1
  for (int kt = 0; kt < 12; kt += 2) {
    if (kt + 1 < 12) S1_LOADS(kt + 1);
    __builtin_amdgcn_sched_barrier(0);
    S1_COMPUTE(0);
    SYNC_RW();
    if (kt + 1 < 12) S1_WRITE(1);
    SYNC_W();
    if (kt + 2 < 12) S1_LOADS(kt + 2);
    __builtin_amdgcn_sched_barrier(0);
    if (kt + 1 < 12) S1_COMPUTE(1);
    SYNC_RW();
    if (kt + 2 < 12) S1_WRITE(0);
    SYNC_W();
  }

  // epilogue: C/D layout col=lane&15, row=(lane>>4)*4+reg
  const int crow = (lane >> 4) << 2;
  const int ccol = lane & 15;
#pragma unroll
  for (int mi = 0; mi < 4; ++mi) {
#pragma unroll
    for (int ri = 0; ri < 4; ++ri) {
      const int lm = wm + mi * 16 + crow + ri;
      if (lm < rows) {
        u16* hb = hbuf + (size_t)(r0 + lm) * HDIM + nt * 64 + wn;
#pragma unroll
        for (int nj = 0; nj < 2; ++nj) {
          const float g = aG[mi][nj][ri];
          const float u = aU[mi][nj][ri];
          const float h = g / (1.0f + __expf(-g)) * u;
          hb[nj * 16 + ccol] = f2bf(h);
        }
      }
    }
  }
}

// ---------------------------------------------------------------------------
// Stage 2: out[tok,:] += h Wd^T.  BM=128, BN=64, BK=64, split-K=2.
// grid = MAXT*24 flat: bid = t*24 + ks*12 + nt. LDS 48KB (3 blocks/CU).
// 16 phases.
// ---------------------------------------------------------------------------
__global__ __launch_bounds__(256, 3) void moe_stage2(
    const u16* __restrict__ hbuf, const int* __restrict__ perm,
    const int* __restrict__ meta, const float* __restrict__ wd,
    float* __restrict__ out) {
  const int t = blockIdx.x / 24;
  if (t >= meta[15]) return;
  const int rem = blockIdx.x - t * 24;
  const int ks = rem / 12;
  const int nt = rem - ks * 12;
  const int e = meta[16 + t];
  const int r0 = meta[48 + t];
  const int rows = min(128, meta[e + 1] - r0);

  __shared__ __align__(16) u16 sA[2][128 * 64];
  __shared__ __align__(16) u16 sB[2][64 * 64];

  const int tid = threadIdx.x;
  const int lane = tid & 63;
  const int wv = tid >> 6;
  const int wm = (wv >> 1) * 64;
  const int wn = (wv & 1) * 32;

  // A staging (bf16 source, no cvt): thread -> (row ar, half ah); 32 bf16
  const int ar = tid >> 1, ah = tid & 1;
  const u16* ap = hbuf + (size_t)(r0 + min(ar, rows - 1)) * HDIM +
                  ks * 1024 + ah * 32;
  // B staging (fp32 Wd): thread -> (row br, quarter bq); 16 floats
  const int br = tid >> 2, bq = tid & 3;
  const float* bp = wd + ((size_t)e * DDIM + nt * 64 + br) * HDIM +
                    ks * 1024 + bq * 16;

  f32x4 acc[4][2] = {};
  uint4 la[4];
  float4 lb[4];

#define S2_LOADS(kt) do {                                            \
    const uint4* qa_ = (const uint4*)(ap + (kt) * 64);               \
    _Pragma("unroll") for (int j = 0; j < 4; ++j) la[j] = qa_[j];    \
    const float4* qb_ = (const float4*)(bp + (kt) * 64);             \
    _Pragma("unroll") for (int j = 0; j < 4; ++j) lb[j] = qb_[j];    \
  } while (0)

#define S2_WRITE(b) do {                                                     \
    const int akey_ = ar & 15, bkey_ = br & 15;                              \
    _Pragma("unroll") for (int j = 0; j < 4; ++j) {                          \
      uint2 lo_ = {la[j].x, la[j].y}, hi_ = {la[j].z, la[j].w};              \
      *(uint2*)&sA[b][ar * 64 + (((ah * 8 + 2 * j)     ^ akey_) << 2)] = lo_;\
      *(uint2*)&sA[b][ar * 64 + (((ah * 8 + 2 * j + 1) ^ akey_) << 2)] = hi_;\
      *(uint2*)&sB[b][br * 64 + (((bq * 4 + j) ^ bkey_) << 2)] = cvt2(lb[j]);\
    }                                                                        \
  } while (0)

#define S2_COMPUTE(b) do {                                           \
    const int fr_ = lane & 15, kb_ = lane >> 4;                      \
    _Pragma("unroll") for (int kh = 0; kh < 2; ++kh) {               \
      const int c0_ = kh * 8 + kb_ * 2;                              \
      bf16x8 a_[4], b_[2];                                           \
      _Pragma("unroll") for (int mi = 0; mi < 4; ++mi)               \
        a_[mi] = frag8(sA[b], wm + mi * 16 + fr_, c0_);              \
      _Pragma("unroll") for (int nj = 0; nj < 2; ++nj)               \
        b_[nj] = frag8(sB[b], wn + nj * 16 + fr_, c0_);              \
      _Pragma("unroll") for (int mi = 0; mi < 4; ++mi)               \
        _Pragma("unroll") for (int nj = 0; nj < 2; ++nj)             \
          acc[mi][nj] = mfma(a_[mi], b_[nj], acc[mi][nj]);           \
    }                                                                \
  } while (0)

  S2_LOADS(0);
  asm volatile("s_waitcnt vmcnt(0)" ::: "memory");
  S2_WRITE(0);
  SYNC_W();

#pragma unroll 1
  for (int kt = 0; kt < 16; kt += 2) {
    if (kt + 1 < 16) S2_LOADS(kt + 1);
    __builtin_amdgcn_sched_barrier(0);
    S2_COMPUTE(0);
    SYNC_RW();
    if (kt + 1 < 16) S2_WRITE(1);
    SYNC_W();
    if (kt + 2 < 16) S2_LOADS(kt + 2);
    __builtin_amdgcn_sched_barrier(0);
    if (kt + 1 < 16) S2_COMPUTE(1);
    SYNC_RW();
    if (kt + 2 < 16) S2_WRITE(0);
    SYNC_W();
  }

  const int crow = (lane >> 4) << 2;
  const int ccol = lane & 15;
#pragma unroll
  for (int mi = 0; mi < 4; ++mi) {
#pragma unroll
    for (int ri = 0; ri < 4; ++ri) {
      const int lm = wm + mi * 16 + crow + ri;
      if (lm < rows) {
        const int tok = perm[r0 + lm];
        float* orow = out + (size_t)tok * DDIM + nt * 64 + wn;
#pragma unroll
        for (int nj = 0; nj < 2; ++nj) {
          atomicAdd(&orow[nj * 16 + ccol], acc[mi][nj][ri]);
        }
      }
    }
  }
}

// ---------------------------------------------------------------------------
extern "C" void kernel_launch(void* const* d_in, const int* in_sizes, int n_in,
                              void* d_out, int out_size, void* d_ws, size_t ws_size,
                              hipStream_t stream) {
  const float* x  = (const float*)d_in[0];
  const int* idx  = (const int*)d_in[1];
  const float* wg = (const float*)d_in[2];
  const float* wu = (const float*)d_in[3];
  const float* wd = (const float*)d_in[4];
  float* out = (float*)d_out;

  int* iws = (int*)d_ws;
  int* meta = iws;        // [0..8] offs, [15] ntiles, [16..47] e, [48..79] r0
  int* perm = iws + 128;  // 2048 ints
  u16* hbuf = (u16*)((char*)d_ws + 16384);  // 2048*2048 bf16 = 8 MB

  hipMemsetAsync(d_out, 0, (size_t)out_size * sizeof(float), stream);
  moe_dispatch<<<1, 256, 0, stream>>>(idx, meta, perm);
  moe_stage1<<<MAXT * 32, 256, 0, stream>>>(x, perm, meta, wg, wu, hbuf);
  moe_stage2<<<MAXT * 24, 256, 0, stream>>>(hbuf, perm, meta, wd, out);
}